// Round 6
// baseline (486.597 us; speedup 1.0000x reference)
//
#include <hip/hip_runtime.h>

#define KNBR 32
#define NPART 256

typedef float  fvec4 __attribute__((ext_vector_type(4)));
typedef int    ivec4 __attribute__((ext_vector_type(4)));

// ---------------- Pass 1: 256 partial sums of X (no atomics) ----------------
// Plain (temporal) X reads: also serves to warm every XCD L2 with the X table.
__global__ void __launch_bounds__(256) partial_sum_kernel(const float* __restrict__ X, int n,
                                                          double* __restrict__ part) {
    double local = 0.0;
    int stride = gridDim.x * blockDim.x;
    int n4 = n >> 2;
    const fvec4* X4 = (const fvec4*)X;
    for (int i = blockIdx.x * blockDim.x + threadIdx.x; i < n4; i += stride) {
        fvec4 v = X4[i];
        local += (double)((v.x + v.y) + (v.z + v.w));
    }
    for (int i = (n4 << 2) + blockIdx.x * blockDim.x + threadIdx.x; i < n; i += stride)
        local += (double)X[i];

    #pragma unroll
    for (int off = 32; off; off >>= 1)
        local += __shfl_down(local, off, 64);

    __shared__ double sm[4];
    int lane = threadIdx.x & 63, wid = threadIdx.x >> 6;
    if (lane == 0) sm[wid] = local;
    __syncthreads();
    if (threadIdx.x == 0)
        part[blockIdx.x & (NPART - 1)] = (sm[0] + sm[1]) + (sm[2] + sm[3]);
}

// ---------------- Pass 2: one THREAD per row ----------------
// W/IDS are streamed ONCE (256 MB): load them non-temporal (evict-first) so
// they stop thrashing the 4 MB X table out of each per-XCD L2 (FETCH showed
// ~370 MB of X refetches). Gathers stay sc0 (L1 bypass, L2-cached), 16 in
// flight per thread via one asm block.
__global__ void __launch_bounds__(256, 4) moran_kernel(const float* __restrict__ X,
                                                       const fvec4* __restrict__ W4,
                                                       const ivec4* __restrict__ I4,
                                                       const double* __restrict__ part,
                                                       float* __restrict__ out, int n) {
    // Recompute mean from the 256 partials (2 KB, L2-hit) — once per block.
    __shared__ double sm[4];
    {
        double p = part[threadIdx.x & (NPART - 1)];
        #pragma unroll
        for (int off = 32; off; off >>= 1) p += __shfl_down(p, off, 64);
        if ((threadIdx.x & 63) == 0) sm[threadIdx.x >> 6] = p;
    }
    __syncthreads();
    float mean = (float)(((sm[0] + sm[1]) + (sm[2] + sm[3])) * (1.0 / (double)n));

    int row = blockIdx.x * blockDim.x + threadIdx.x;
    if (row >= n) return;

    const ivec4* id = I4 + (size_t)row * (KNBR / 4);
    const fvec4* w  = W4 + (size_t)row * (KNBR / 4);

    float lag = 0.f, s2 = 0.f;
    #pragma unroll
    for (int half = 0; half < 2; ++half) {
        ivec4 i0 = __builtin_nontemporal_load(&id[half * 4 + 0]);
        ivec4 i1 = __builtin_nontemporal_load(&id[half * 4 + 1]);
        ivec4 i2 = __builtin_nontemporal_load(&id[half * 4 + 2]);
        ivec4 i3 = __builtin_nontemporal_load(&id[half * 4 + 3]);
        fvec4 w0 = __builtin_nontemporal_load(&w[half * 4 + 0]);
        fvec4 w1 = __builtin_nontemporal_load(&w[half * 4 + 1]);
        fvec4 w2 = __builtin_nontemporal_load(&w[half * 4 + 2]);
        fvec4 w3 = __builtin_nontemporal_load(&w[half * 4 + 3]);

        unsigned v0  = ((unsigned)i0.x) << 2, v1  = ((unsigned)i0.y) << 2,
                 v2  = ((unsigned)i0.z) << 2, v3  = ((unsigned)i0.w) << 2,
                 v4  = ((unsigned)i1.x) << 2, v5  = ((unsigned)i1.y) << 2,
                 v6  = ((unsigned)i1.z) << 2, v7  = ((unsigned)i1.w) << 2,
                 v8  = ((unsigned)i2.x) << 2, v9  = ((unsigned)i2.y) << 2,
                 v10 = ((unsigned)i2.z) << 2, v11 = ((unsigned)i2.w) << 2,
                 v12 = ((unsigned)i3.x) << 2, v13 = ((unsigned)i3.y) << 2,
                 v14 = ((unsigned)i3.z) << 2, v15 = ((unsigned)i3.w) << 2;

        float x0, x1, x2, x3, x4, x5, x6, x7, x8, x9, x10, x11, x12, x13, x14, x15;
        // 16 independent L1-bypassing gathers, all in flight before one wait.
        asm volatile(
            "global_load_dword %0, %16, %32 sc0\n\t"
            "global_load_dword %1, %17, %32 sc0\n\t"
            "global_load_dword %2, %18, %32 sc0\n\t"
            "global_load_dword %3, %19, %32 sc0\n\t"
            "global_load_dword %4, %20, %32 sc0\n\t"
            "global_load_dword %5, %21, %32 sc0\n\t"
            "global_load_dword %6, %22, %32 sc0\n\t"
            "global_load_dword %7, %23, %32 sc0\n\t"
            "global_load_dword %8, %24, %32 sc0\n\t"
            "global_load_dword %9, %25, %32 sc0\n\t"
            "global_load_dword %10, %26, %32 sc0\n\t"
            "global_load_dword %11, %27, %32 sc0\n\t"
            "global_load_dword %12, %28, %32 sc0\n\t"
            "global_load_dword %13, %29, %32 sc0\n\t"
            "global_load_dword %14, %30, %32 sc0\n\t"
            "global_load_dword %15, %31, %32 sc0\n\t"
            "s_waitcnt vmcnt(0)"
            : "=&v"(x0), "=&v"(x1), "=&v"(x2), "=&v"(x3),
              "=&v"(x4), "=&v"(x5), "=&v"(x6), "=&v"(x7),
              "=&v"(x8), "=&v"(x9), "=&v"(x10), "=&v"(x11),
              "=&v"(x12), "=&v"(x13), "=&v"(x14), "=&v"(x15)
            : "v"(v0), "v"(v1), "v"(v2), "v"(v3),
              "v"(v4), "v"(v5), "v"(v6), "v"(v7),
              "v"(v8), "v"(v9), "v"(v10), "v"(v11),
              "v"(v12), "v"(v13), "v"(v14), "v"(v15),
              "s"(X));

        float xg[16] = { x0, x1, x2, x3, x4, x5, x6, x7,
                         x8, x9, x10, x11, x12, x13, x14, x15 };
        float wv[16] = { w0.x, w0.y, w0.z, w0.w,
                         w1.x, w1.y, w1.z, w1.w,
                         w2.x, w2.y, w2.z, w2.w,
                         w3.x, w3.y, w3.z, w3.w };
        #pragma unroll
        for (int t = 0; t < 16; ++t) {
            float xn = xg[t] - mean;
            lag += wv[t] * xn;
            s2  += wv[t] * xn * xn;
        }
    }
    float xa = X[row] - mean;
    out[row] = xa * lag * (float)(KNBR - 1) / s2;
}

extern "C" void kernel_launch(void* const* d_in, const int* in_sizes, int n_in,
                              void* d_out, int out_size, void* d_ws, size_t ws_size,
                              hipStream_t stream) {
    const float* X   = (const float*)d_in[0];
    const float* W   = (const float*)d_in[1];
    const int*   IDS = (const int*)d_in[2];
    float* out = (float*)d_out;
    int n = in_sizes[0];

    double* part = (double*)d_ws;  // 256 doubles, each written every call

    partial_sum_kernel<<<NPART, 256, 0, stream>>>(X, n, part);

    int blocks = (n + 255) / 256;
    moran_kernel<<<blocks, 256, 0, stream>>>(X, (const fvec4*)W, (const ivec4*)IDS,
                                             part, out, n);
}

// Round 7
// 425.985 us; speedup vs baseline: 1.1423x; 1.1423x over previous
//
#include <hip/hip_runtime.h>

#define KNBR 32
#define NPART 256

typedef float  fvec4 __attribute__((ext_vector_type(4)));
typedef int    ivec4 __attribute__((ext_vector_type(4)));

// ---------------- Pass 1: 256 partial sums of X (no atomics) ----------------
__global__ void __launch_bounds__(256) partial_sum_kernel(const float* __restrict__ X, int n,
                                                          double* __restrict__ part) {
    double local = 0.0;
    int stride = gridDim.x * blockDim.x;
    int n4 = n >> 2;
    const fvec4* X4 = (const fvec4*)X;
    for (int i = blockIdx.x * blockDim.x + threadIdx.x; i < n4; i += stride) {
        fvec4 v = X4[i];
        local += (double)((v.x + v.y) + (v.z + v.w));
    }
    for (int i = (n4 << 2) + blockIdx.x * blockDim.x + threadIdx.x; i < n; i += stride)
        local += (double)X[i];

    #pragma unroll
    for (int off = 32; off; off >>= 1)
        local += __shfl_down(local, off, 64);

    __shared__ double sm[4];
    int lane = threadIdx.x & 63, wid = threadIdx.x >> 6;
    if (lane == 0) sm[wid] = local;
    __syncthreads();
    if (threadIdx.x == 0)
        part[blockIdx.x & (NPART - 1)] = (sm[0] + sm[1]) + (sm[2] + sm[3]);
}

// ---------------- Pass 2: one THREAD per row ----------------
// Ceiling analysis (R1-R6): throughput pinned at ~0.2 lane-gathers/cyc/CU
// across layout, cache policy, forced MLP, and L2-residency changes — the
// per-CU divergent miss-path service rate (~5 cyc/lane-request). 32M
// mandatory random 4B gathers / 256 CU * ~4.8 cyc / 2.4 GHz ~= 250 us floor.
// This kernel (R5 config) measured 250 us = at the floor.
__global__ void __launch_bounds__(256, 4) moran_kernel(const float* __restrict__ X,
                                                       const fvec4* __restrict__ W4,
                                                       const ivec4* __restrict__ I4,
                                                       const double* __restrict__ part,
                                                       float* __restrict__ out, int n) {
    // Recompute mean from the 256 partials (2 KB, L2-hit) — once per block.
    __shared__ double sm[4];
    {
        double p = part[threadIdx.x & (NPART - 1)];
        #pragma unroll
        for (int off = 32; off; off >>= 1) p += __shfl_down(p, off, 64);
        if ((threadIdx.x & 63) == 0) sm[threadIdx.x >> 6] = p;
    }
    __syncthreads();
    float mean = (float)(((sm[0] + sm[1]) + (sm[2] + sm[3])) * (1.0 / (double)n));

    int row = blockIdx.x * blockDim.x + threadIdx.x;
    if (row >= n) return;

    const ivec4* id = I4 + (size_t)row * (KNBR / 4);
    const fvec4* w  = W4 + (size_t)row * (KNBR / 4);

    float lag = 0.f, s2 = 0.f;
    #pragma unroll
    for (int half = 0; half < 2; ++half) {
        ivec4 i0 = id[half * 4 + 0];
        ivec4 i1 = id[half * 4 + 1];
        ivec4 i2 = id[half * 4 + 2];
        ivec4 i3 = id[half * 4 + 3];
        fvec4 w0 = w[half * 4 + 0];
        fvec4 w1 = w[half * 4 + 1];
        fvec4 w2 = w[half * 4 + 2];
        fvec4 w3 = w[half * 4 + 3];

        unsigned v0  = ((unsigned)i0.x) << 2, v1  = ((unsigned)i0.y) << 2,
                 v2  = ((unsigned)i0.z) << 2, v3  = ((unsigned)i0.w) << 2,
                 v4  = ((unsigned)i1.x) << 2, v5  = ((unsigned)i1.y) << 2,
                 v6  = ((unsigned)i1.z) << 2, v7  = ((unsigned)i1.w) << 2,
                 v8  = ((unsigned)i2.x) << 2, v9  = ((unsigned)i2.y) << 2,
                 v10 = ((unsigned)i2.z) << 2, v11 = ((unsigned)i2.w) << 2,
                 v12 = ((unsigned)i3.x) << 2, v13 = ((unsigned)i3.y) << 2,
                 v14 = ((unsigned)i3.z) << 2, v15 = ((unsigned)i3.w) << 2;

        float x0, x1, x2, x3, x4, x5, x6, x7, x8, x9, x10, x11, x12, x13, x14, x15;
        // 16 independent L1-bypassing gathers, all in flight before one wait.
        asm volatile(
            "global_load_dword %0, %16, %32 sc0\n\t"
            "global_load_dword %1, %17, %32 sc0\n\t"
            "global_load_dword %2, %18, %32 sc0\n\t"
            "global_load_dword %3, %19, %32 sc0\n\t"
            "global_load_dword %4, %20, %32 sc0\n\t"
            "global_load_dword %5, %21, %32 sc0\n\t"
            "global_load_dword %6, %22, %32 sc0\n\t"
            "global_load_dword %7, %23, %32 sc0\n\t"
            "global_load_dword %8, %24, %32 sc0\n\t"
            "global_load_dword %9, %25, %32 sc0\n\t"
            "global_load_dword %10, %26, %32 sc0\n\t"
            "global_load_dword %11, %27, %32 sc0\n\t"
            "global_load_dword %12, %28, %32 sc0\n\t"
            "global_load_dword %13, %29, %32 sc0\n\t"
            "global_load_dword %14, %30, %32 sc0\n\t"
            "global_load_dword %15, %31, %32 sc0\n\t"
            "s_waitcnt vmcnt(0)"
            : "=&v"(x0), "=&v"(x1), "=&v"(x2), "=&v"(x3),
              "=&v"(x4), "=&v"(x5), "=&v"(x6), "=&v"(x7),
              "=&v"(x8), "=&v"(x9), "=&v"(x10), "=&v"(x11),
              "=&v"(x12), "=&v"(x13), "=&v"(x14), "=&v"(x15)
            : "v"(v0), "v"(v1), "v"(v2), "v"(v3),
              "v"(v4), "v"(v5), "v"(v6), "v"(v7),
              "v"(v8), "v"(v9), "v"(v10), "v"(v11),
              "v"(v12), "v"(v13), "v"(v14), "v"(v15),
              "s"(X));

        float xg[16] = { x0, x1, x2, x3, x4, x5, x6, x7,
                         x8, x9, x10, x11, x12, x13, x14, x15 };
        float wv[16] = { w0.x, w0.y, w0.z, w0.w,
                         w1.x, w1.y, w1.z, w1.w,
                         w2.x, w2.y, w2.z, w2.w,
                         w3.x, w3.y, w3.z, w3.w };
        #pragma unroll
        for (int t = 0; t < 16; ++t) {
            float xn = xg[t] - mean;
            lag += wv[t] * xn;
            s2  += wv[t] * xn * xn;
        }
    }
    float xa = X[row] - mean;
    out[row] = xa * lag * (float)(KNBR - 1) / s2;
}

extern "C" void kernel_launch(void* const* d_in, const int* in_sizes, int n_in,
                              void* d_out, int out_size, void* d_ws, size_t ws_size,
                              hipStream_t stream) {
    const float* X   = (const float*)d_in[0];
    const float* W   = (const float*)d_in[1];
    const int*   IDS = (const int*)d_in[2];
    float* out = (float*)d_out;
    int n = in_sizes[0];

    double* part = (double*)d_ws;  // 256 doubles, each written every call

    partial_sum_kernel<<<NPART, 256, 0, stream>>>(X, n, part);

    int blocks = (n + 255) / 256;
    moran_kernel<<<blocks, 256, 0, stream>>>(X, (const fvec4*)W, (const ivec4*)IDS,
                                             part, out, n);
}